// Round 3
// baseline (71.703 us; speedup 1.0000x reference)
//
#include <hip/hip_runtime.h>
#include <math.h>

#define N_RAYS 131072
#define N_PTS  128
#define FAR_DELTA 1e10f

// DPP cross-lane move: result[lane] = valid(src lane) ? src[srclane] : old[lane].
// row_shl:N = 0x100|N (lane i <- lane i+N), row_shr:N = 0x110|N (lane i <- lane i-N).
// DPP rows are 16 lanes — exactly one ray group, so shifts never cross rays.
template<int CTRL>
__device__ __forceinline__ float dpp_mov(float src, float old) {
    return __builtin_bit_cast(float, __builtin_amdgcn_update_dpp(
        __builtin_bit_cast(int, old), __builtin_bit_cast(int, src),
        CTRL, 0xF, 0xF, false));
}

struct Tile {
    float4 d0, d1, g0, g1;          // depth, density (8 floats each)
    float4 f0, f1, f2, f3, f4, f5;  // 24 feature floats
};

__device__ __forceinline__ Tile load_tile(const float* __restrict__ density,
                                          const float* __restrict__ feature,
                                          const float* __restrict__ depthv,
                                          int ray, int sub) {
    Tile t;
    const size_t sbase = (size_t)ray * N_PTS + sub * 8;
    t.d0 = *reinterpret_cast<const float4*>(depthv  + sbase);
    t.d1 = *reinterpret_cast<const float4*>(depthv  + sbase + 4);
    t.g0 = *reinterpret_cast<const float4*>(density + sbase);
    t.g1 = *reinterpret_cast<const float4*>(density + sbase + 4);
    const float* fb = feature + (size_t)ray * (N_PTS * 3) + sub * 24;
    t.f0 = *reinterpret_cast<const float4*>(fb +  0);
    t.f1 = *reinterpret_cast<const float4*>(fb +  4);
    t.f2 = *reinterpret_cast<const float4*>(fb +  8);
    t.f3 = *reinterpret_cast<const float4*>(fb + 12);
    t.f4 = *reinterpret_cast<const float4*>(fb + 16);
    t.f5 = *reinterpret_cast<const float4*>(fb + 20);
    return t;
}

__device__ __forceinline__ void compute_tile(const Tile& tl, int ray, int sub,
                                             float* __restrict__ out) {
    const float dv[8] = {tl.d0.x, tl.d0.y, tl.d0.z, tl.d0.w,
                         tl.d1.x, tl.d1.y, tl.d1.z, tl.d1.w};
    const float sg[8] = {tl.g0.x, tl.g0.y, tl.g0.z, tl.g0.w,
                         tl.g1.x, tl.g1.y, tl.g1.z, tl.g1.w};
    const float ff[24] = {tl.f0.x, tl.f0.y, tl.f0.z, tl.f0.w,
                          tl.f1.x, tl.f1.y, tl.f1.z, tl.f1.w,
                          tl.f2.x, tl.f2.y, tl.f2.z, tl.f2.w,
                          tl.f3.x, tl.f3.y, tl.f3.z, tl.f3.w,
                          tl.f4.x, tl.f4.y, tl.f4.z, tl.f4.w,
                          tl.f5.x, tl.f5.y, tl.f5.z, tl.f5.w};

    // deltas: within-lane diffs + first depth of the next lane (row_shl:1).
    const float dn = dpp_mov<0x101>(dv[0], 0.0f);
    float dl[8];
    #pragma unroll
    for (int j = 0; j < 7; ++j) dl[j] = dv[j + 1] - dv[j];
    dl[7] = (sub == 15) ? FAR_DELTA : (dn - dv[7]);

    // t_j = exp(-sigma_j * delta_j); in-lane inclusive products p_j.
    float t[8], p[8];
    #pragma unroll
    for (int j = 0; j < 8; ++j) t[j] = __expf(-sg[j] * dl[j]);
    p[0] = t[0];
    #pragma unroll
    for (int j = 1; j < 8; ++j) p[j] = p[j - 1] * t[j];

    // Cross-lane inclusive product scan of per-lane product (row_shr Kogge-Stone).
    float scan = p[7];
    scan *= dpp_mov<0x111>(scan, 1.0f);
    scan *= dpp_mov<0x112>(scan, 1.0f);
    scan *= dpp_mov<0x114>(scan, 1.0f);
    scan *= dpp_mov<0x118>(scan, 1.0f);
    const float excl = dpp_mov<0x111>(scan, 1.0f);  // exclusive prefix

    float fx = 0.f, fy = 0.f, fz = 0.f, st = 0.f, sd = 0.f;
    #pragma unroll
    for (int j = 0; j < 8; ++j) {
        const float T = (j == 0) ? excl : excl * p[j - 1];
        const float w = fmaf(-T, t[j], T);          // T*(1-t)
        fx = fmaf(w, ff[3 * j + 0], fx);
        fy = fmaf(w, ff[3 * j + 1], fy);
        fz = fmaf(w, ff[3 * j + 2], fz);
        const float ts = (T < 1.0f) ? t[j] : 0.0f;
        st += ts;
        sd = fmaf(ts, dv[j], sd);
    }

    // Cross-lane sum reductions to lane sub==0 (row_shl tree, 0-fill identity).
    #define RED16(x)                 \
        x += dpp_mov<0x108>(x, 0.f); \
        x += dpp_mov<0x104>(x, 0.f); \
        x += dpp_mov<0x102>(x, 0.f); \
        x += dpp_mov<0x101>(x, 0.f);
    RED16(fx) RED16(fy) RED16(fz) RED16(st) RED16(sd)
    #undef RED16

    if (sub == 0) {
        out[(size_t)ray * 3 + 0] = fx;
        out[(size_t)ray * 3 + 1] = fy;
        out[(size_t)ray * 3 + 2] = fz;
        const float dep = sd / st;
        out[(size_t)N_RAYS * 3 + ray] = (dep == 0.0f) ? INFINITY : dep;
    }
}

// 16 lanes/ray, 8 samples/lane. Each 256-thread block processes 64 rays as
// 4 tiles of 16 rays, software-pipelined 2 deep: next tile's 10 dwordx4
// loads are in flight while the current tile computes.
__global__ __launch_bounds__(256) void volrender_kernel(
    const float* __restrict__ density,
    const float* __restrict__ feature,
    const float* __restrict__ depthv,
    float* __restrict__ out)
{
    const int tid = threadIdx.x;
    const int sub = tid & 15;
    const int grp = tid >> 4;                 // 0..15: ray slot within tile
    const int rayBase = blockIdx.x * 64 + grp;

    Tile A = load_tile(density, feature, depthv, rayBase +  0, sub);
    Tile B = load_tile(density, feature, depthv, rayBase + 16, sub);
    compute_tile(A, rayBase +  0, sub, out);
    A = load_tile(density, feature, depthv, rayBase + 32, sub);
    compute_tile(B, rayBase + 16, sub, out);
    B = load_tile(density, feature, depthv, rayBase + 48, sub);
    compute_tile(A, rayBase + 32, sub, out);
    compute_tile(B, rayBase + 48, sub, out);
}

extern "C" void kernel_launch(void* const* d_in, const int* in_sizes, int n_in,
                              void* d_out, int out_size, void* d_ws, size_t ws_size,
                              hipStream_t stream) {
    const float* density = (const float*)d_in[0];
    const float* feature = (const float*)d_in[1];
    const float* depthv  = (const float*)d_in[2];
    float* out = (float*)d_out;

    const int grid = N_RAYS / 64;   // 2048 blocks, 64 rays per block
    volrender_kernel<<<grid, 256, 0, stream>>>(density, feature, depthv, out);
}